// Round 15
// baseline (361.991 us; speedup 1.0000x reference)
//
#include <hip/hip_runtime.h>
#include <cmath>

// x [B=4096][T=512][D=4], H=32, gates 4H=128 (PyTorch order i,f,g,o).
constexpr int T   = 512;
constexpr int D   = 4;
constexpr int H   = 32;
constexpr int BT  = 16;    // batch cols per block — ALL real
constexpr int BLK = 256;   // 4 waves: (layer, unit-half) — R16 topology
constexpr int NSL = 4;     // h ring slots (slack 3 between producer/consumer)

constexpr float LOG2E     = 1.44269504088896340736f;
constexpr float NEG2LOG2E = -2.88539008177792681472f;

// x staged as FULL zero-padded B-fragments (8 shorts/t). Col stride 4104
// shorts = 2052 dwords ≡ 4 (mod 32): broadcast b128 reads 2-way = free.
constexpr int XSTRIDE = 4104;
// h row stride 40 shorts = 20 dwords: b128 frag reads have bank-quad index
// (5*nl+q) mod 8 — exactly 2-way (nl vs nl+8) = free.
constexpr int HSTR = 40;

typedef short bf8 __attribute__((ext_vector_type(8)));  // 8 bf16 (4 VGPRs)
typedef float f4  __attribute__((ext_vector_type(4)));  // MFMA C/D
typedef float f2  __attribute__((ext_vector_type(2)));  // packed-f32 pair

// fp32 -> bf16 round-to-nearest-even (staging path)
static __device__ __forceinline__ short bf16_rtn(float v) {
    unsigned u = __float_as_uint(v);
    u += 0x7FFFu + ((u >> 16) & 1u);
    return (short)(u >> 16);
}

// R24 = R16 work distribution (4 waves: layer x unit-half — the proven
// argmin) with the per-step 4-way __syncthreads replaced by PAIRWISE flag
// sync + lagged rings:
//  - 4-slot h0/h1 rings; per-wave step counters in LDS (flg[4]).
//  - L1 wave step i waits: fl[partner] >= i (h0(i-1) other half),
//    fl[L2a/b] >= i-3 (slot i&3's old h0(i-4) consumed).
//  - L2 wave step j waits: fl[partner] >= j (h1(j-1) other half),
//    fl[L1a/b] >= j+1 (h0(j) complete).
//  - Producer: data ds_write -> __threadfence_block (lgkm drain) -> flag.
//    Consumer: spin volatile poll (+s_sleep) -> __threadfence_block -> read.
//  - Rationale: R17 proved >=480cy spare issue/step (2x issue, same wall) —
//    the ~550cy residue is chain+sync; 4-way convergence jitter at every one
//    of 513 steps is the untested term. This removes it with ZERO change to
//    act distribution (R18/19/22's fatal cost). L1 slips up to 3 ahead.
__global__ __launch_bounds__(BLK, 1) void lstm_flag(
    const float* __restrict__ x,
    const float* __restrict__ W_ih0, const float* __restrict__ W_hh0,
    const float* __restrict__ b_ih0, const float* __restrict__ b_hh0,
    const float* __restrict__ W_ih1, const float* __restrict__ W_hh1,
    const float* __restrict__ b_ih1, const float* __restrict__ b_hh1,
    const float* __restrict__ W_out, const float* __restrict__ b_out,
    float* __restrict__ out)
{
    __shared__ __align__(16) short xbf[16 * XSTRIDE];    // 131.3 KB staged x frags
    __shared__ __align__(16) short h0r[NSL][16][HSTR];   // h0 ring, 5.1 KB
    __shared__ __align__(16) short h1r[NSL][16][HSTR];   // h1 ring, 5.1 KB
    __shared__ __align__(16) float h1f[16][36];          // final h1 fp32 for head
    __shared__ __align__(16) int   flg[4];               // per-wave step counters

    const int tid   = threadIdx.x;
    const int w     = tid >> 6;
    const int lane  = tid & 63;
    const int q     = lane >> 4;       // quad
    const int nl    = lane & 15;       // batch col (all real)
    const int layer = w >> 1;          // 0: L1 (waves 0,1), 1: L2 (waves 2,3)
    const int ug    = (w & 1) << 4;    // unit group offset 0 / 16
    const int b0    = blockIdx.x * BT;

    // ---- stage x -> zero-padded bf16 fragments (R15-proven path) ----
    for (int idx = tid; idx < 16 * T; idx += BLK) {
        const int col = idx & 15;
        const int t   = idx >> 4;
        float4 xv = *(const float4*)(x + ((size_t)(b0 + col) * T + t) * D);
        bf8 v = {0, 0, 0, 0, 0, 0, 0, 0};
        v[0] = bf16_rtn(xv.x); v[1] = bf16_rtn(xv.y);
        v[2] = bf16_rtn(xv.z); v[3] = bf16_rtn(xv.w);
        *(bf8*)&xbf[col * XSTRIDE + t * 8] = v;
    }
    // zero both rings (slot 3 = h(-1) = 0) + flags
    for (int idx = tid; idx < NSL * 16 * HSTR; idx += BLK) {
        (&h0r[0][0][0])[idx] = 0;
        (&h1r[0][0][0])[idx] = 0;
    }
    if (tid < 4) flg[tid] = 0;

    // ---- weights: tile g = gate type. A-frag row = 32g + ug + nl, k = 8q+j.
    const float* W1 = layer ? W_ih1 : W_hh0;
    bf8 w1[4], w2[4];
    f4  bias[4];
    #pragma unroll
    for (int g = 0; g < 4; ++g) {
        const float sc = (g == 2) ? NEG2LOG2E : -LOG2E;
        const int row = 32 * g + ug + nl;
        #pragma unroll
        for (int j = 0; j < 8; ++j) {
            w1[g][j] = bf16_rtn(W1[row * H + 8 * q + j] * sc);
            float v2 = layer ? W_hh1[row * H + 8 * q + j]
                             : ((q == 0 && j < 4) ? W_ih0[row * D + j] : 0.0f);
            w2[g][j] = bf16_rtn(v2 * sc);
        }
        #pragma unroll
        for (int r = 0; r < 4; ++r) {
            const int gr = 32 * g + ug + 4 * q + r;
            bias[g][r] = sc * (layer ? (b_ih1[gr] + b_hh1[gr])
                                     : (b_ih0[gr] + b_hh0[gr]));
        }
    }

    // cell state, fp32, lane-local — two packed pairs (r01, r23)
    f2 cA; cA.x = 0.0f; cA.y = 0.0f;
    f2 cB; cB.x = 0.0f; cB.y = 0.0f;

    const short* xcol = &xbf[nl * XSTRIDE];

    __syncthreads();   // staging + zeroed rings + flags visible to all

    // ---- packed activation for one r-pair (R16-proven) ----
    auto actpair = [&](f2& c2, float zi0, float zi1, float zf0, float zf1,
                       float zg0, float zg1, float zo0, float zo1,
                       unsigned& pkd, f2& hv) {
        f2 ei, ef, eg, eo, ec;
        ei.x = __builtin_amdgcn_exp2f(zi0); ei.y = __builtin_amdgcn_exp2f(zi1);
        ef.x = __builtin_amdgcn_exp2f(zf0); ef.y = __builtin_amdgcn_exp2f(zf1);
        eg.x = __builtin_amdgcn_exp2f(zg0); eg.y = __builtin_amdgcn_exp2f(zg1);
        eo.x = __builtin_amdgcn_exp2f(zo0); eo.y = __builtin_amdgcn_exp2f(zo1);
        f2 D1 = 1.0f + ef;
        f2 D2 = (1.0f + ei) * (1.0f + eg);
        f2 Dm = D1 * D2;
        float R = __builtin_amdgcn_rcpf(Dm.x * Dm.y);
        f2 rD; rD.x = R * Dm.y; rD.y = R * Dm.x;
        c2 = (c2 * D2 + (1.0f - eg) * D1) * rD;
        ec.x = __builtin_amdgcn_exp2f(c2.x * NEG2LOG2E);
        ec.y = __builtin_amdgcn_exp2f(c2.y * NEG2LOG2E);
        f2 Do = (1.0f + eo) * (1.0f + ec);
        float Ro = __builtin_amdgcn_rcpf(Do.x * Do.y);
        f2 ro; ro.x = Ro * Do.y; ro.y = Ro * Do.x;
        hv = (1.0f - ec) * ro;
        asm("v_cvt_pk_bf16_f32 %0, %1, %2" : "=v"(pkd) : "v"(hv.x), "v"(hv.y));
    };

    volatile int* vf = flg;

    if (layer == 0) {
        // ================= L1: h0(i) = f(h0(i-1), x(i)) =================
        #pragma unroll 1
        for (int i = 0; i < T; ++i) {
            // partner half of h0(i-1) + slot-reuse safety vs L2 lag
            while ((vf[w ^ 1] < i) | (vf[2] < i - 3) | (vf[3] < i - 3))
                __builtin_amdgcn_s_sleep(1);
            __threadfence_block();                         // acquire
            bf8 b2 = *(const bf8*)&xcol[i * 8];            // x(i)
            bf8 b1 = *(const bf8*)&h0r[(i - 1) & (NSL - 1)][nl][8 * q];
            f4 acc[4];
            #pragma unroll
            for (int g = 0; g < 4; ++g) {
                f4 A = __builtin_amdgcn_mfma_f32_16x16x32_bf16(w2[g], b2, bias[g], 0, 0, 0);
                A    = __builtin_amdgcn_mfma_f32_16x16x32_bf16(w1[g], b1, A,       0, 0, 0);
                acc[g] = A;
            }
            unsigned pk0, pk1; f2 hvA, hvB;
            actpair(cA, acc[0][0], acc[0][1], acc[1][0], acc[1][1],
                        acc[2][0], acc[2][1], acc[3][0], acc[3][1], pk0, hvA);
            actpair(cB, acc[0][2], acc[0][3], acc[1][2], acc[1][3],
                        acc[2][2], acc[2][3], acc[3][2], acc[3][3], pk1, hvB);
            int2 hh; hh.x = (int)pk0; hh.y = (int)pk1;
            *(int2*)&h0r[i & (NSL - 1)][nl][ug + 4 * q] = hh;
            __threadfence_block();                         // release (lgkm drain)
            vf[w] = i + 1;                                 // publish step done
        }
    } else {
        // ================= L2: h1(j) = f(h1(j-1), h0(j)) =================
        #pragma unroll 1
        for (int j = 0; j < T; ++j) {
            // partner half of h1(j-1) + both halves of h0(j)
            while ((vf[w ^ 1] < j) | (vf[0] < j + 1) | (vf[1] < j + 1))
                __builtin_amdgcn_s_sleep(1);
            __threadfence_block();                         // acquire
            bf8 b2 = *(const bf8*)&h1r[(j - 1) & (NSL - 1)][nl][8 * q];
            bf8 b1 = *(const bf8*)&h0r[j & (NSL - 1)][nl][8 * q];
            f4 acc[4];
            #pragma unroll
            for (int g = 0; g < 4; ++g) {
                f4 A = __builtin_amdgcn_mfma_f32_16x16x32_bf16(w2[g], b2, bias[g], 0, 0, 0);
                A    = __builtin_amdgcn_mfma_f32_16x16x32_bf16(w1[g], b1, A,       0, 0, 0);
                acc[g] = A;
            }
            unsigned pk0, pk1; f2 hvA, hvB;
            actpair(cA, acc[0][0], acc[0][1], acc[1][0], acc[1][1],
                        acc[2][0], acc[2][1], acc[3][0], acc[3][1], pk0, hvA);
            actpair(cB, acc[0][2], acc[0][3], acc[1][2], acc[1][3],
                        acc[2][2], acc[2][3], acc[3][2], acc[3][3], pk1, hvB);
            int2 hh; hh.x = (int)pk0; hh.y = (int)pk1;
            *(int2*)&h1r[j & (NSL - 1)][nl][ug + 4 * q] = hh;
            if (j == T - 1) {   // h1(T-1), fp32, for the output head
                float4 hw;
                hw.x = hvA.x; hw.y = hvA.y; hw.z = hvB.x; hw.w = hvB.y;
                *(float4*)&h1f[nl][ug + 4 * q] = hw;
            }
            __threadfence_block();                         // release
            vf[w] = j + 1;
        }
    }

    __syncthreads();   // h1f complete

    // ---- output head: out[b0+n] = b_out + W_out . h1(T-1) ----
    if (tid < BT) {
        float acc = b_out[0];
        #pragma unroll
        for (int u = 0; u < H; ++u) acc = fmaf(W_out[u], h1f[tid][u], acc);
        out[b0 + tid] = acc;
    }
}

extern "C" void kernel_launch(void* const* d_in, const int* in_sizes, int n_in,
                              void* d_out, int out_size, void* d_ws, size_t ws_size,
                              hipStream_t stream) {
    const float* x     = (const float*)d_in[0];
    const float* W_ih0 = (const float*)d_in[1];
    const float* W_hh0 = (const float*)d_in[2];
    const float* b_ih0 = (const float*)d_in[3];
    const float* b_hh0 = (const float*)d_in[4];
    const float* W_ih1 = (const float*)d_in[5];
    const float* W_hh1 = (const float*)d_in[6];
    const float* b_ih1 = (const float*)d_in[7];
    const float* b_hh1 = (const float*)d_in[8];
    const float* W_out = (const float*)d_in[9];
    const float* b_out = (const float*)d_in[10];
    float* out = (float*)d_out;

    const int B = out_size;          // 4096
    lstm_flag<<<B / BT, BLK, 0, stream>>>(x, W_ih0, W_hh0, b_ih0, b_hh0,
                                          W_ih1, W_hh1, b_ih1, b_hh1,
                                          W_out, b_out, out);
}